// Round 1
// baseline (4004.287 us; speedup 1.0000x reference)
//
#include <hip/hip_runtime.h>
#include <hip/hip_bf16.h>

// Problem constants
#define B_    2
#define S_    4096
#define D_    2048
#define V_    50257
#define NROWS (B_*(S_-1))      // 8190 valid rows
#define NPAD  8192             // padded rows (multiple of BM)
#define BN_   128
#define NCH   393              // ceil(50257/128) v-chunks
#define VPAD  (NCH*BN_)        // 50304
#define VSPLIT 16
#define CPS   25               // ceil(393/16) chunks per split
#define BM_   128
#define BK_   64
#define RT_   (NPAD/BM_)       // 64 row tiles

typedef __attribute__((ext_vector_type(8))) short s16x8;
typedef __attribute__((ext_vector_type(4))) float f32x4;

// fp32 -> bf16 round-to-nearest-even (bit manipulation; no header dependency)
__device__ __forceinline__ short f2bf(float x) {
    unsigned u = __float_as_uint(x);
    u += 0x7fffu + ((u >> 16) & 1u);
    return (short)(u >> 16);
}

// async global->LDS, 16 bytes per lane (wave-uniform LDS base + lane*16)
__device__ __forceinline__ void load_lds16(const short* g, short* l) {
    __builtin_amdgcn_global_load_lds(
        (const __attribute__((address_space(1))) void*)g,
        (__attribute__((address_space(3))) void*)l,
        16, 0, 0);
}

// ---------------- conversion kernels ----------------

// W [V, D] fp32 -> Wbf [VPAD, D] bf16 (rows >= V zeroed)
__global__ void conv_w(const float* __restrict__ w, short* __restrict__ o) {
    const long long total = (long long)VPAD * (D_ / 8);
    for (long long i = (long long)blockIdx.x * blockDim.x + threadIdx.x;
         i < total; i += (long long)gridDim.x * blockDim.x) {
        const int v = (int)(i / (D_ / 8));
        const int d = (int)(i % (D_ / 8)) * 8;
        s16x8 ov;
        if (v < V_) {
            const float* src = w + (long long)v * D_ + d;
            f32x4 a = *(const f32x4*)(src);
            f32x4 b = *(const f32x4*)(src + 4);
            ov[0]=f2bf(a[0]); ov[1]=f2bf(a[1]); ov[2]=f2bf(a[2]); ov[3]=f2bf(a[3]);
            ov[4]=f2bf(b[0]); ov[5]=f2bf(b[1]); ov[6]=f2bf(b[2]); ov[7]=f2bf(b[3]);
        } else {
            ov = (s16x8)0;
        }
        *(s16x8*)&o[i * 8] = ov;
    }
}

// embeddings [B,S,D] fp32 -> Abf [NPAD, D] bf16, shifted: row n = emb[n/4095, n%4095, :]
__global__ void conv_a(const float* __restrict__ e, short* __restrict__ o) {
    const long long total = (long long)NPAD * (D_ / 8);
    for (long long i = (long long)blockIdx.x * blockDim.x + threadIdx.x;
         i < total; i += (long long)gridDim.x * blockDim.x) {
        const int n = (int)(i / (D_ / 8));
        const int d = (int)(i % (D_ / 8)) * 8;
        s16x8 ov;
        if (n < NROWS) {
            const int b = n / (S_ - 1);
            const int s = n % (S_ - 1);
            const float* src = e + ((long long)b * S_ + s) * D_ + d;
            f32x4 a = *(const f32x4*)(src);
            f32x4 bb = *(const f32x4*)(src + 4);
            ov[0]=f2bf(a[0]); ov[1]=f2bf(a[1]); ov[2]=f2bf(a[2]); ov[3]=f2bf(a[3]);
            ov[4]=f2bf(bb[0]); ov[5]=f2bf(bb[1]); ov[6]=f2bf(bb[2]); ov[7]=f2bf(bb[3]);
        } else {
            ov = (s16x8)0;
        }
        *(s16x8*)&o[i * 8] = ov;
    }
}

// bias [V] -> biasp [VPAD] (pad with -1e30 so padded cols vanish in softmax)
__global__ void conv_bias(const float* __restrict__ b, float* __restrict__ o) {
    const int i = blockIdx.x * blockDim.x + threadIdx.x;
    if (i < VPAD) o[i] = (i < V_) ? b[i] : -1.0e30f;
}

// labels [B,S] int32 -> ypad [NPAD]: y_n = labels[b, s+1]; pad rows -> -100
__global__ void conv_y(const int* __restrict__ lab, int* __restrict__ o) {
    const int n = blockIdx.x * blockDim.x + threadIdx.x;
    if (n < NPAD) {
        if (n < NROWS) {
            const int b = n / (S_ - 1);
            const int s = n % (S_ - 1);
            o[n] = lab[b * S_ + s + 1];
        } else {
            o[n] = -100;
        }
    }
}

// ---------------- main fused GEMM + online-LSE kernel ----------------
// Grid: RT_ * VSPLIT blocks, 256 threads (4 waves).
// Block (rt, vs): rows [rt*128, +128), v-chunks [vs*25, min(+25, 393)).
// Wave w owns rows [rt*128 + w*32, +32) x all 128 cols of the current chunk.
__global__ __launch_bounds__(256, 2) void lse_main(
    const short* __restrict__ A, const short* __restrict__ W,
    const float* __restrict__ bias, const int* __restrict__ y,
    float* __restrict__ pm, float* __restrict__ ps, float* __restrict__ tgt)
{
    __shared__ __align__(16) short As[BM_ * BK_];
    __shared__ __align__(16) short Bs[BN_ * BK_];

    const int tid  = threadIdx.x;
    const int wave = tid >> 6;
    const int lane = tid & 63;
    const int l15  = lane & 15;
    const int lhi  = lane >> 4;
    const int bid  = blockIdx.x;
    const int rt   = bid / VSPLIT;
    const int vs   = bid % VSPLIT;
    const int mbase = rt * BM_;
    const int wrow  = mbase + wave * 32;
    const int c0 = vs * CPS;
    const int c1 = (c0 + CPS < NCH) ? (c0 + CPS) : NCH;

    // per-lane: 8 row slots (2 mi x 4 reg), replicated across the 16-lane col group
    int yr[2][4];
    float rm[2][4], rs[2][4];
    #pragma unroll
    for (int mi = 0; mi < 2; ++mi)
        #pragma unroll
        for (int r = 0; r < 4; ++r) {
            yr[mi][r] = y[wrow + mi * 16 + lhi * 4 + r];
            rm[mi][r] = -3.0e38f;
            rs[mi][r] = 0.f;
        }

    const int srow = lane >> 3;        // row within an 8-row staging chunk
    const int scol = (lane & 7) * 8;   // bf16 col offset (16B per lane)

    for (int c = c0; c < c1; ++c) {
        const int nbase = c * BN_;
        f32x4 acc[2][8];
        #pragma unroll
        for (int mi = 0; mi < 2; ++mi)
            #pragma unroll
            for (int ni = 0; ni < 8; ++ni) acc[mi][ni] = (f32x4)0.0f;

        for (int kt = 0; kt < D_ / BK_; ++kt) {
            const int kb = kt * BK_;
            // stage A,B tiles: 16 chunks of 1KB each, wave w handles chunks w*4..w*4+3
            #pragma unroll
            for (int i = 0; i < 4; ++i) {
                const int j  = wave * 4 + i;
                const int lr = j * 8 + srow;
                load_lds16(A + (long long)(mbase + lr) * D_ + kb + scol, &As[j * 512]);
                load_lds16(W + (long long)(nbase + lr) * D_ + kb + scol, &Bs[j * 512]);
            }
            __syncthreads();
            #pragma unroll
            for (int kk = 0; kk < BK_; kk += 32) {
                s16x8 af[2];
                #pragma unroll
                for (int mi = 0; mi < 2; ++mi)
                    af[mi] = *(const s16x8*)&As[(wave * 32 + mi * 16 + l15) * BK_ + kk + lhi * 8];
                #pragma unroll
                for (int ni = 0; ni < 8; ++ni) {
                    s16x8 bf = *(const s16x8*)&Bs[(ni * 16 + l15) * BK_ + kk + lhi * 8];
                    acc[0][ni] = __builtin_amdgcn_mfma_f32_16x16x32_bf16(af[0], bf, acc[0][ni], 0, 0, 0);
                    acc[1][ni] = __builtin_amdgcn_mfma_f32_16x16x32_bf16(af[1], bf, acc[1][ni], 0, 0, 0);
                }
            }
            __syncthreads();
        }

        // epilogue: online logsumexp update over this chunk's 128 columns
        float bv[8];
        #pragma unroll
        for (int ni = 0; ni < 8; ++ni) bv[ni] = bias[nbase + ni * 16 + l15];

        #pragma unroll
        for (int mi = 0; mi < 2; ++mi) {
            #pragma unroll
            for (int r = 0; r < 4; ++r) {
                float v[8];
                float cm = -3.0e38f;
                #pragma unroll
                for (int ni = 0; ni < 8; ++ni) {
                    v[ni] = acc[mi][ni][r] + bv[ni];
                    cm = fmaxf(cm, v[ni]);
                }
                #pragma unroll
                for (int d = 1; d < 16; d <<= 1) cm = fmaxf(cm, __shfl_xor(cm, d, 16));
                const float nm = fmaxf(rm[mi][r], cm);
                float sl = 0.f;
                #pragma unroll
                for (int ni = 0; ni < 8; ++ni) sl += __expf(v[ni] - nm);
                #pragma unroll
                for (int d = 1; d < 16; d <<= 1) sl += __shfl_xor(sl, d, 16);
                rs[mi][r] = rs[mi][r] * __expf(rm[mi][r] - nm) + sl;
                rm[mi][r] = nm;
                // target logit: exactly one (row, col==y) hit across the whole grid
                const int yy = yr[mi][r];
                #pragma unroll
                for (int ni = 0; ni < 8; ++ni)
                    if (nbase + ni * 16 + l15 == yy) atomicAdd(tgt, v[ni]);
            }
        }
    }

    // write per-(split,row) partials; 16-lane group replicates, lane l15==0 writes
    if (l15 == 0) {
        #pragma unroll
        for (int mi = 0; mi < 2; ++mi)
            #pragma unroll
            for (int r = 0; r < 4; ++r) {
                const int row = wrow + mi * 16 + lhi * 4 + r;
                pm[(long long)vs * NPAD + row] = rm[mi][r];
                ps[(long long)vs * NPAD + row] = rs[mi][r];
            }
    }
}

// ---------------- finalize: combine partials -> loss scalar ----------------
__global__ void finalize(const float* __restrict__ pm, const float* __restrict__ ps,
                         const int* __restrict__ y, const float* __restrict__ tgt,
                         float* __restrict__ out)
{
    __shared__ float sred[256];
    __shared__ int scnt[256];
    const int tid = threadIdx.x;
    float lsum = 0.f;
    int lcnt = 0;
    for (int n = tid; n < NROWS; n += 256) {
        if (y[n] == -100) continue;
        float m = -3.0e38f, s = 0.f;
        #pragma unroll
        for (int v = 0; v < VSPLIT; ++v) {
            const float m2 = pm[(long long)v * NPAD + n];
            const float s2 = ps[(long long)v * NPAD + n];
            const float nm = fmaxf(m, m2);
            s = s * __expf(m - nm) + s2 * __expf(m2 - nm);
            m = nm;
        }
        lsum += m + logf(s);
        lcnt++;
    }
    sred[tid] = lsum;
    scnt[tid] = lcnt;
    __syncthreads();
    for (int off = 128; off > 0; off >>= 1) {
        if (tid < off) { sred[tid] += sred[tid + off]; scnt[tid] += scnt[tid + off]; }
        __syncthreads();
    }
    if (tid == 0) {
        const float cnt = (float)scnt[0];
        out[0] = (sred[0] - tgt[0]) / fmaxf(cnt, 1.f);
    }
}

// ---------------- launcher ----------------
extern "C" void kernel_launch(void* const* d_in, const int* in_sizes, int n_in,
                              void* d_out, int out_size, void* d_ws, size_t ws_size,
                              hipStream_t stream) {
    const float* emb    = (const float*)d_in[0];
    const float* wgt    = (const float*)d_in[1];
    const float* bias   = (const float*)d_in[2];
    const int*   labels = (const int*)d_in[3];
    float* out = (float*)d_out;

    char* ws = (char*)d_ws;
    const size_t WBF_B  = (size_t)VPAD * D_ * 2;   // 196.5 MiB
    const size_t ABF_B  = (size_t)NPAD * D_ * 2;   // 32 MiB
    const size_t BIAS_B = (size_t)VPAD * 4;
    const size_t Y_B    = (size_t)NPAD * 4;
    const size_t PM_B   = (size_t)VSPLIT * NPAD * 4;

    short* Wbf   = (short*)(ws);
    short* Abf   = (short*)(ws + WBF_B);
    float* biasp = (float*)(ws + WBF_B + ABF_B);
    int*   ypad  = (int*)  (ws + WBF_B + ABF_B + BIAS_B);
    float* pm    = (float*)(ws + WBF_B + ABF_B + BIAS_B + Y_B);
    float* psum  = (float*)(ws + WBF_B + ABF_B + BIAS_B + Y_B + PM_B);
    float* tgt   = (float*)(ws + WBF_B + ABF_B + BIAS_B + Y_B + 2 * PM_B);

    hipMemsetAsync(tgt, 0, sizeof(float), stream);

    conv_w<<<2048, 256, 0, stream>>>(wgt, Wbf);
    conv_a<<<512, 256, 0, stream>>>(emb, Abf);
    conv_bias<<<(VPAD + 255) / 256, 256, 0, stream>>>(bias, biasp);
    conv_y<<<(NPAD + 255) / 256, 256, 0, stream>>>(labels, ypad);

    lse_main<<<RT_ * VSPLIT, 256, 0, stream>>>(Abf, Wbf, biasp, ypad, pm, psum, tgt);

    finalize<<<1, 256, 0, stream>>>(pm, psum, ypad, tgt, out);
}

// Round 2
// 2935.928 us; speedup vs baseline: 1.3639x; 1.3639x over previous
//
#include <hip/hip_runtime.h>
#include <hip/hip_bf16.h>

// Problem constants
#define B_    2
#define S_    4096
#define D_    2048
#define V_    50257
#define NROWS (B_*(S_-1))      // 8190 valid rows
#define NPAD  8192             // padded rows (multiple of BM)
#define BN_   128
#define NCH   393              // ceil(50257/128) v-chunks
#define VPAD  (NCH*BN_)        // 50304
#define VSPLIT 16
#define CPS   25               // ceil(393/16) chunks per split
#define BM_   128
#define BK_   64
#define RT_   (NPAD/BM_)       // 64 row tiles

typedef __attribute__((ext_vector_type(8))) short s16x8;
typedef __attribute__((ext_vector_type(4))) float f32x4;

// fp32 -> bf16 round-to-nearest-even
__device__ __forceinline__ short f2bf(float x) {
    unsigned u = __float_as_uint(x);
    u += 0x7fffu + ((u >> 16) & 1u);
    return (short)(u >> 16);
}

// async global->LDS, 16 bytes per lane (wave-uniform LDS base + lane*16)
__device__ __forceinline__ void load_lds16(const short* g, short* l) {
    __builtin_amdgcn_global_load_lds(
        (const __attribute__((address_space(1))) void*)g,
        (__attribute__((address_space(3))) void*)l,
        16, 0, 0);
}

// ---------------- conversion kernels ----------------

__global__ void conv_w(const float* __restrict__ w, short* __restrict__ o) {
    const long long total = (long long)VPAD * (D_ / 8);
    for (long long i = (long long)blockIdx.x * blockDim.x + threadIdx.x;
         i < total; i += (long long)gridDim.x * blockDim.x) {
        const int v = (int)(i / (D_ / 8));
        const int d = (int)(i % (D_ / 8)) * 8;
        s16x8 ov;
        if (v < V_) {
            const float* src = w + (long long)v * D_ + d;
            f32x4 a = *(const f32x4*)(src);
            f32x4 b = *(const f32x4*)(src + 4);
            ov[0]=f2bf(a[0]); ov[1]=f2bf(a[1]); ov[2]=f2bf(a[2]); ov[3]=f2bf(a[3]);
            ov[4]=f2bf(b[0]); ov[5]=f2bf(b[1]); ov[6]=f2bf(b[2]); ov[7]=f2bf(b[3]);
        } else {
            ov = (s16x8)0;
        }
        *(s16x8*)&o[i * 8] = ov;
    }
}

__global__ void conv_a(const float* __restrict__ e, short* __restrict__ o) {
    const long long total = (long long)NPAD * (D_ / 8);
    for (long long i = (long long)blockIdx.x * blockDim.x + threadIdx.x;
         i < total; i += (long long)gridDim.x * blockDim.x) {
        const int n = (int)(i / (D_ / 8));
        const int d = (int)(i % (D_ / 8)) * 8;
        s16x8 ov;
        if (n < NROWS) {
            const int b = n / (S_ - 1);
            const int s = n % (S_ - 1);
            const float* src = e + ((long long)b * S_ + s) * D_ + d;
            f32x4 a = *(const f32x4*)(src);
            f32x4 bb = *(const f32x4*)(src + 4);
            ov[0]=f2bf(a[0]); ov[1]=f2bf(a[1]); ov[2]=f2bf(a[2]); ov[3]=f2bf(a[3]);
            ov[4]=f2bf(bb[0]); ov[5]=f2bf(bb[1]); ov[6]=f2bf(bb[2]); ov[7]=f2bf(bb[3]);
        } else {
            ov = (s16x8)0;
        }
        *(s16x8*)&o[i * 8] = ov;
    }
}

__global__ void conv_bias(const float* __restrict__ b, float* __restrict__ o) {
    const int i = blockIdx.x * blockDim.x + threadIdx.x;
    if (i < VPAD) o[i] = (i < V_) ? b[i] : -1.0e30f;
}

__global__ void conv_y(const int* __restrict__ lab, int* __restrict__ o) {
    const int n = blockIdx.x * blockDim.x + threadIdx.x;
    if (n < NPAD) {
        if (n < NROWS) {
            const int b = n / (S_ - 1);
            const int s = n % (S_ - 1);
            o[n] = lab[b * S_ + s + 1];
        } else {
            o[n] = -100;
        }
    }
}

// ---------------- main fused GEMM + online-LSE kernel ----------------
// LDS layout: row-major [128][64] bf16 per tile, but each row's eight
// 8-element column groups are stored permuted: LDS[r][g] = G[r][g ^ (r&7)].
// (rule #21: global_load_lds writes linearly -> swizzle the SOURCE address,
// apply the same XOR on the ds_read side. Involution, bijective per row.)
// This breaks the 16-way bank conflict of the 128B row stride down to a
// free 2-way.
__global__ __launch_bounds__(256, 2) void lse_main(
    const short* __restrict__ A, const short* __restrict__ W,
    const float* __restrict__ bias, const int* __restrict__ y,
    float* __restrict__ pm, float* __restrict__ ps, float* __restrict__ tgt)
{
    __shared__ __align__(16) short As[BM_ * BK_];
    __shared__ __align__(16) short Bs[BN_ * BK_];

    const int tid  = threadIdx.x;
    const int wave = tid >> 6;
    const int lane = tid & 63;
    const int l15  = lane & 15;
    const int lhi  = lane >> 4;

    // vs-major + XCD-chunked block order: each XCD's contiguous 128-block
    // chunk spans only 2 vs values -> co-resident blocks share the W panel
    // in that XCD's L2.
    const int bid0 = blockIdx.x;
    const int swz  = (bid0 & 7) * (RT_ * VSPLIT / 8) + (bid0 >> 3); // 1024 % 8 == 0
    const int vs   = swz / RT_;
    const int rt   = swz % RT_;

    const int mbase = rt * BM_;
    const int wrow  = mbase + wave * 32;
    const int c0 = vs * CPS;
    const int c1 = (c0 + CPS < NCH) ? (c0 + CPS) : NCH;

    int yr[2][4];
    float rm[2][4], rs[2][4];
    #pragma unroll
    for (int mi = 0; mi < 2; ++mi)
        #pragma unroll
        for (int r = 0; r < 4; ++r) {
            yr[mi][r] = y[wrow + mi * 16 + lhi * 4 + r];
            rm[mi][r] = -3.0e38f;
            rs[mi][r] = 0.f;
        }

    const int srow = lane >> 3;                    // row within 8-row chunk
    const int scol = (((lane & 7) ^ srow)) * 8;    // SWIZZLED source col group

    for (int c = c0; c < c1; ++c) {
        const int nbase = c * BN_;
        f32x4 acc[2][8];
        #pragma unroll
        for (int mi = 0; mi < 2; ++mi)
            #pragma unroll
            for (int ni = 0; ni < 8; ++ni) acc[mi][ni] = (f32x4)0.0f;

        for (int kt = 0; kt < D_ / BK_; ++kt) {
            const int kb = kt * BK_;
            #pragma unroll
            for (int i = 0; i < 4; ++i) {
                const int j  = wave * 4 + i;
                const int lr = j * 8 + srow;
                load_lds16(A + (long long)(mbase + lr) * D_ + kb + scol, &As[j * 512]);
                load_lds16(W + (long long)(nbase + lr) * D_ + kb + scol, &Bs[j * 512]);
            }
            __syncthreads();
            #pragma unroll
            for (int kk = 0; kk < BK_; kk += 32) {
                // swizzled column group for this lane's fragment rows
                const int gsw = (((kk >> 3) + lhi) ^ (l15 & 7)) * 8;
                s16x8 af[2];
                #pragma unroll
                for (int mi = 0; mi < 2; ++mi)
                    af[mi] = *(const s16x8*)&As[(wave * 32 + mi * 16 + l15) * BK_ + gsw];
                #pragma unroll
                for (int ni = 0; ni < 8; ++ni) {
                    s16x8 bf = *(const s16x8*)&Bs[(ni * 16 + l15) * BK_ + gsw];
                    acc[0][ni] = __builtin_amdgcn_mfma_f32_16x16x32_bf16(af[0], bf, acc[0][ni], 0, 0, 0);
                    acc[1][ni] = __builtin_amdgcn_mfma_f32_16x16x32_bf16(af[1], bf, acc[1][ni], 0, 0, 0);
                }
            }
            __syncthreads();
        }

        // epilogue: online logsumexp update over this chunk's 128 columns
        float bv[8];
        #pragma unroll
        for (int ni = 0; ni < 8; ++ni) bv[ni] = bias[nbase + ni * 16 + l15];

        #pragma unroll
        for (int mi = 0; mi < 2; ++mi) {
            #pragma unroll
            for (int r = 0; r < 4; ++r) {
                float v[8];
                float cm = -3.0e38f;
                #pragma unroll
                for (int ni = 0; ni < 8; ++ni) {
                    v[ni] = acc[mi][ni][r] + bv[ni];
                    cm = fmaxf(cm, v[ni]);
                }
                #pragma unroll
                for (int d = 1; d < 16; d <<= 1) cm = fmaxf(cm, __shfl_xor(cm, d, 16));
                const float nm = fmaxf(rm[mi][r], cm);
                float sl = 0.f;
                #pragma unroll
                for (int ni = 0; ni < 8; ++ni) sl += __expf(v[ni] - nm);
                #pragma unroll
                for (int d = 1; d < 16; d <<= 1) sl += __shfl_xor(sl, d, 16);
                rs[mi][r] = rs[mi][r] * __expf(rm[mi][r] - nm) + sl;
                rm[mi][r] = nm;
                const int yy = yr[mi][r];
                #pragma unroll
                for (int ni = 0; ni < 8; ++ni)
                    if (nbase + ni * 16 + l15 == yy) atomicAdd(tgt, v[ni]);
            }
        }
    }

    if (l15 == 0) {
        #pragma unroll
        for (int mi = 0; mi < 2; ++mi)
            #pragma unroll
            for (int r = 0; r < 4; ++r) {
                const int row = wrow + mi * 16 + lhi * 4 + r;
                pm[(long long)vs * NPAD + row] = rm[mi][r];
                ps[(long long)vs * NPAD + row] = rs[mi][r];
            }
    }
}

// ---------------- finalize (two-stage, parallel) ----------------
// accum[0] = sum of lse over valid rows, accum[1] = valid count
__global__ void finalize1(const float* __restrict__ pm, const float* __restrict__ ps,
                          const int* __restrict__ y, float* __restrict__ accum)
{
    __shared__ float s_sum[4], s_cnt[4];
    const int n = blockIdx.x * blockDim.x + threadIdx.x;
    float lsum = 0.f, lcnt = 0.f;
    if (n < NROWS && y[n] != -100) {
        float m = -3.0e38f, s = 0.f;
        #pragma unroll
        for (int v = 0; v < VSPLIT; ++v) {
            const float m2 = pm[(long long)v * NPAD + n];
            const float s2 = ps[(long long)v * NPAD + n];
            const float nm = fmaxf(m, m2);
            s = s * __expf(m - nm) + s2 * __expf(m2 - nm);
            m = nm;
        }
        lsum = m + logf(s);
        lcnt = 1.f;
    }
    #pragma unroll
    for (int d = 1; d < 64; d <<= 1) {
        lsum += __shfl_xor(lsum, d, 64);
        lcnt += __shfl_xor(lcnt, d, 64);
    }
    const int wv = threadIdx.x >> 6;
    if ((threadIdx.x & 63) == 0) { s_sum[wv] = lsum; s_cnt[wv] = lcnt; }
    __syncthreads();
    if (threadIdx.x == 0) {
        float bs = s_sum[0] + s_sum[1] + s_sum[2] + s_sum[3];
        float bc = s_cnt[0] + s_cnt[1] + s_cnt[2] + s_cnt[3];
        atomicAdd(&accum[0], bs);
        atomicAdd(&accum[1], bc);
    }
}

__global__ void finalize2(const float* __restrict__ accum, const float* __restrict__ tgt,
                          float* __restrict__ out)
{
    out[0] = (accum[0] - tgt[0]) / fmaxf(accum[1], 1.f);
}

// ---------------- launcher ----------------
extern "C" void kernel_launch(void* const* d_in, const int* in_sizes, int n_in,
                              void* d_out, int out_size, void* d_ws, size_t ws_size,
                              hipStream_t stream) {
    const float* emb    = (const float*)d_in[0];
    const float* wgt    = (const float*)d_in[1];
    const float* bias   = (const float*)d_in[2];
    const int*   labels = (const int*)d_in[3];
    float* out = (float*)d_out;

    char* ws = (char*)d_ws;
    const size_t WBF_B  = (size_t)VPAD * D_ * 2;   // 196.5 MiB
    const size_t ABF_B  = (size_t)NPAD * D_ * 2;   // 32 MiB
    const size_t BIAS_B = (size_t)VPAD * 4;
    const size_t Y_B    = (size_t)NPAD * 4;
    const size_t PM_B   = (size_t)VSPLIT * NPAD * 4;

    short* Wbf   = (short*)(ws);
    short* Abf   = (short*)(ws + WBF_B);
    float* biasp = (float*)(ws + WBF_B + ABF_B);
    int*   ypad  = (int*)  (ws + WBF_B + ABF_B + BIAS_B);
    float* pm    = (float*)(ws + WBF_B + ABF_B + BIAS_B + Y_B);
    float* psum  = (float*)(ws + WBF_B + ABF_B + BIAS_B + Y_B + PM_B);
    float* tgt   = (float*)(ws + WBF_B + ABF_B + BIAS_B + Y_B + 2 * PM_B);
    // tgt[0] = target-logit sum, tgt[1] = lse sum, tgt[2] = valid count
    float* accum = tgt + 1;

    hipMemsetAsync(tgt, 0, 3 * sizeof(float), stream);

    conv_w<<<2048, 256, 0, stream>>>(wgt, Wbf);
    conv_a<<<512, 256, 0, stream>>>(emb, Abf);
    conv_bias<<<(VPAD + 255) / 256, 256, 0, stream>>>(bias, biasp);
    conv_y<<<(NPAD + 255) / 256, 256, 0, stream>>>(labels, ypad);

    lse_main<<<RT_ * VSPLIT, 256, 0, stream>>>(Abf, Wbf, biasp, ypad, pm, psum, tgt);

    finalize1<<<(NROWS + 255) / 256, 256, 0, stream>>>(pm, psum, ypad, accum);
    finalize2<<<1, 1, 0, stream>>>(accum, tgt, out);
}